// Round 8
// baseline (1220.242 us; speedup 1.0000x reference)
//
#include <hip/hip_runtime.h>
#include <cstdint>
#include <cstddef>

// CTC-CRF logZ forward: S=1024, NZ=5, linear-domain, damped pow2 renorm
// (R7 consumer body, unchanged - proven correct & conflict-free).
// R2/R4/R7 all pinned at 762us: per-CU HBM streaming ceiling (~26 GB/s/CU =
// MSHR x 64B / ~900cyc HBM latency; m13: 6.29TB/s / 256CU = 24.6 GB/s/CU).
// Fix: 224 PREFETCHER blocks warm the consumer's XCD L2 ahead of the
// recursion (L2 hit ~200cyc -> ~4.5x per-CU BW for the same MSHR budget).
// Prefetcher bid serves batch n=(bid-32)%32; 32==0 (mod 8) so both share
// bid%8 -> same XCD under round-robin dispatch (perf heuristic only;
// correctness placement-independent). Throttle: <=24 steps ahead of an
// agent-scope progress counter in d_ws (published every 8 steps), so the
// live window (24x20KB x 4 batches/XCD ~ 1.9MB) fits the 4MB XCD L2.
// d_ws progress table re-zeroed per launch by a stream-ordered init kernel.

#define NB 32
#define SD 1024
#define CD 5120
#define AHEAD 24
#define DONE_S 0x7fffffff

typedef float f4a __attribute__((ext_vector_type(4), aligned(4)));

__device__ __forceinline__ float fexp2(float x) { return __builtin_amdgcn_exp2f(x); }
__device__ __forceinline__ float flog2(float x) { return __builtin_amdgcn_logf(x); }

template <int CTRL>
__device__ __forceinline__ float dppq(float v) {
  return __int_as_float(
      __builtin_amdgcn_update_dpp(0, __float_as_int(v), CTRL, 0xF, 0xF, true));
}

__global__ void init_prog(int* prog) {
  if (threadIdx.x < NB) prog[threadIdx.x] = 0;
}

__global__ void __launch_bounds__(1024) ctc_logz(const float* __restrict__ scores,
                                                 float* __restrict__ out,
                                                 int* __restrict__ prog, int T) {
  const int bid = blockIdx.x;

  if (bid >= NB) {
    // ---------------- prefetcher path (no LDS, no barriers) ----------------
    const int pb = bid - NB;
    const int n = pb & 31;               // consumer batch (same XCD mod-8)
    const int k = pb >> 5;               // 0..6
    const int wid = threadIdx.x >> 6;
    const int lane = threadIdx.x & 63;
    const int q = k * 16 + wid;          // wave-unit 0..111
    const float* sb = scores + (size_t)n * CD + (size_t)lane * 4;
    const size_t tstr = (size_t)NB * CD;
    float acc = 0.f;
    for (int t = q; t < T; t += 112) {
      int p = __hip_atomic_load(&prog[n], __ATOMIC_RELAXED, __HIP_MEMORY_SCOPE_AGENT);
      while (p != DONE_S && p + AHEAD <= t) {
        __builtin_amdgcn_s_sleep(32);
        p = __hip_atomic_load(&prog[n], __ATOMIC_RELAXED, __HIP_MEMORY_SCOPE_AGENT);
      }
      if (p == DONE_S) break;            // consumer finished
      const float* s = sb + (size_t)t * tstr;
#pragma unroll
      for (int i = 0; i < 20; ++i) {     // 20 x dwordx4/wave = 20KB slab
        f4a v = *(const f4a*)(s + i * 256);
        acc += v.x + v.y + v.z + v.w;    // keep loads alive (full width)
      }
    }
    asm volatile("" ::"v"(acc));         // DCE sink
    return;
  }

  // ------------------------- consumer path (R7) --------------------------
  __shared__ float ap[2 * SD];
  __shared__ float red[16];

  const int u = threadIdx.x;
  const int n = bid;
  const int lane = u & 63;
  const int wid = u >> 6;
  const int p = u >> 2, c = u & 3;
  const int rdoff = (c << 8) | (p ^ (c << 3));   // slot(p + 256c), swizzled
  const int wroff = u ^ ((u & 0x300) >> 5);      // slot(u)

  ap[u] = 1.f; ap[SD + u] = 1.f;
  float a_cur = 1.f;
  float nLf = 0.f;
  int Lnext = 0, cacc = 0;

  const float K = 1.44269504088896340736f;
  const float LN2 = 0.69314718055994530942f;

  const float* sn = scores + (size_t)n * CD + (size_t)u * 5;
  const size_t tstr = (size_t)NB * CD;
  const size_t str4 = 4 * tstr;

  auto CP = [&](int t, const f4a& qa, float qb) {
    const int rb = ((t + 1) & 1) * SD;
    const float vr = ap[rb + rdoff];    // pred read, conflict-free
    const float R = ap[rb];             // uniform addr -> broadcast
    const float p0 = dppq<0x00>(vr);    // A[p]
    const float p1 = dppq<0x55>(vr);    // A[256+p]
    const float p2 = dppq<0xAA>(vr);    // A[512+p]
    const float p3 = dppq<0xFF>(vr);    // A[768+p]
    float e0 = fexp2(__builtin_fmaf(qa.x, K, nLf));
    float e1 = fexp2(__builtin_fmaf(qa.y, K, nLf));
    float e2 = fexp2(__builtin_fmaf(qa.z, K, nLf));
    float e3 = fexp2(__builtin_fmaf(qa.w, K, nLf));
    float e4 = fexp2(__builtin_fmaf(qb,   K, nLf));
    float s = e0 * a_cur;
    s = __builtin_fmaf(e1, p0, s);
    s = __builtin_fmaf(e2, p1, s);
    s = __builtin_fmaf(e3, p2, s);
    s = __builtin_fmaf(e4, p3, s);
    a_cur = s;
    cacc += Lnext;
    ap[(t & 1) * SD + wroff] = s;
    const int xb = ((__float_as_int(R) >> 23) & 0xFF) - 127;
    Lnext = xb >> 2;                    // damped controller: lag 1, gain 1/4
    nLf = (float)(-Lnext);
    if (((t & 7) == 0) && (u == 0))     // publish progress for prefetchers
      __hip_atomic_store(&prog[n], t, __ATOMIC_RELAXED, __HIP_MEMORY_SCOPE_AGENT);
    asm volatile("s_waitcnt lgkmcnt(0)\n\ts_barrier" ::: "memory");
  };

#define PRO(cc)                                                             \
  const float* P##cc = sn + (size_t)((cc) < T ? (cc) : T - 1) * tstr;       \
  f4a qa##cc = *(const f4a*)P##cc;                                          \
  float qb##cc = P##cc[4];                                                  \
  P##cc += str4;
  PRO(0) PRO(1) PRO(2) PRO(3)
#undef PRO

  __syncthreads();

#define RL(cc)                                                              \
  qa##cc = *(const f4a*)P##cc;                                              \
  qb##cc = P##cc[4];                                                        \
  P##cc += str4;

  int t = 0;
  for (; t + 8 <= T; t += 4) {
    CP(t + 0, qa0, qb0); RL(0)
    CP(t + 1, qa1, qb1); RL(1)
    CP(t + 2, qa2, qb2); RL(2)
    CP(t + 3, qa3, qb3); RL(3)
  }
#undef RL

#define EPI1(cc)                                                            \
  if (t + (cc) < T) {                                                       \
    CP(t + (cc), qa##cc, qb##cc);                                           \
    if (t + 4 + (cc) < T) { qa##cc = *(const f4a*)P##cc; qb##cc = P##cc[4]; }\
  }
  EPI1(0) EPI1(1) EPI1(2) EPI1(3)
#undef EPI1
  t += 4;
#define EPI2(cc) if (t + (cc) < T) CP(t + (cc), qa##cc, qb##cc);
  EPI2(0) EPI2(1) EPI2(2) EPI2(3)
#undef EPI2

  if (u == 0)
    __hip_atomic_store(&prog[n], DONE_S, __ATOMIC_RELAXED, __HIP_MEMORY_SCOPE_AGENT);

  float v = a_cur;
#pragma unroll
  for (int d = 1; d < 64; d <<= 1) v += __shfl_xor(v, d, 64);
  if (lane == 0) red[wid] = v;
  __syncthreads();
  if (u == 0) {
    float ssum = red[0];
#pragma unroll
    for (int i = 1; i < 16; ++i) ssum += red[i];
    out[n] = LN2 * ((float)cacc + flog2(ssum));
  }
}

extern "C" void kernel_launch(void* const* d_in, const int* in_sizes, int n_in,
                              void* d_out, int out_size, void* d_ws, size_t ws_size,
                              hipStream_t stream) {
  const float* scores = (const float*)d_in[0];
  float* out = (float*)d_out;
  int* prog = (int*)d_ws;
  const long long tot = (long long)in_sizes[0];
  const int T = (int)(tot / ((long long)NB * CD));
  init_prog<<<dim3(1), dim3(64), 0, stream>>>(prog);
  ctc_logz<<<dim3(256), dim3(1024), 0, stream>>>(scores, out, prog, T);
}

// Round 9
// 640.117 us; speedup vs baseline: 1.9063x; 1.9063x over previous
//
#include <hip/hip_runtime.h>
#include <cstdint>
#include <cstddef>

// CTC-CRF logZ forward: S=1024, NZ=5, linear-domain, damped pow2 renorm
// (R7 consumer body, proven correct/conflict-free, pinned at 762us).
// Hypothesis: consumer is outstanding-lines x latency limited (~22B/cyc/CU,
// ~50% L3 hits already). This round: L2/L3 pre-warm by helper blocks with
// ALL R8 contention sources removed:
//  - LDS padded >80KB -> hardware-guaranteed 1 block/CU (no co-residency).
//  - 96 blocks total: 32 consumers + 2 helpers/batch (parity-split chunks).
//  - helpers fetch 1 dword per 64B line (320 lines/step), <=AHEAD steps
//    ahead of the consumer's progress counter; skip chunks already passed.
//  - polls: 1 lane/block, s_sleep(64) (~1.7us), LDS broadcast; prog entries
//    strided 1 cache line each. Consumer NEVER waits (graceful fallback).
//  - helper bids {32+n,64+n} = n (mod 8): same XCD as consumer n under
//    round-robin dispatch (perf heuristic only; L3 catches otherwise).

#define NB 32
#define SD 1024
#define CD 5120
#define AHEAD 24
#define CHUNK 8
#define DONE_S 0x7fffffff

typedef float f4a __attribute__((ext_vector_type(4), aligned(4)));

__device__ __forceinline__ float fexp2(float x) { return __builtin_amdgcn_exp2f(x); }
__device__ __forceinline__ float flog2(float x) { return __builtin_amdgcn_logf(x); }

template <int CTRL>
__device__ __forceinline__ float dppq(float v) {
  return __int_as_float(
      __builtin_amdgcn_update_dpp(0, __float_as_int(v), CTRL, 0xF, 0xF, true));
}

__global__ void init_prog(int* prog) {
  const int i = threadIdx.x;
  if (i < NB) prog[i * 64] = 0;
}

__global__ void __launch_bounds__(1024) ctc_logz(const float* __restrict__ scores,
                                                 float* __restrict__ out,
                                                 int* __restrict__ prog, int T) {
  __shared__ float ap[2 * SD];
  __shared__ float red[16];
  __shared__ float pad[19456];   // 76KB pad -> total LDS >80KB -> 1 block/CU
  __shared__ int pmsg;

  const int bid = blockIdx.x;
  const int u = threadIdx.x;
  if (T < 0) { pad[u] = 1.f; out[0] = pad[u ^ 1]; }  // keep pad allocated

  const size_t tstr = (size_t)NB * CD;

  if (bid >= NB) {
    // ------------------- helper / L2-L3 pre-warm path -------------------
    const int h = bid - NB;
    const int n = h & 31;          // batch (same XCD as consumer n, mod 8)
    const int parity = h >> 5;     // 0 or 1: chunk parity split
    const float* base = scores + (size_t)n * CD;
    float acc = 0.f;
    for (int c = parity; c * CHUNK < T; c += 2) {
      const int t0 = c * CHUNK;
      int p;
      for (;;) {
        if (u == 0)
          pmsg = __hip_atomic_load(&prog[n * 64], __ATOMIC_RELAXED,
                                   __HIP_MEMORY_SCOPE_AGENT);
        __syncthreads();
        p = pmsg;
        __syncthreads();
        if (p == DONE_S || t0 < p + AHEAD) break;
        __builtin_amdgcn_s_sleep(64);   // ~4096 cyc between polls
      }
      if (p == DONE_S) break;
      if (t0 + CHUNK <= p) continue;    // consumer already past this chunk
      if (u < 320) {                    // 320 lines x 64B = one 20KB step
        const float* cb = base + (size_t)t0 * tstr + (size_t)u * 16;
        const int lim = (T - t0 < CHUNK) ? (T - t0) : CHUNK;
        for (int s = 0; s < lim; ++s) { acc += *cb; cb += tstr; }
      }
    }
    asm volatile("" ::"v"(acc));        // DCE sink
    return;
  }

  // ------------------------- consumer path (R7) --------------------------
  const int n = bid;
  const int lane = u & 63;
  const int wid = u >> 6;
  const int p = u >> 2, c = u & 3;
  const int rdoff = (c << 8) | (p ^ (c << 3));   // slot(p + 256c), swizzled
  const int wroff = u ^ ((u & 0x300) >> 5);      // slot(u)

  ap[u] = 1.f; ap[SD + u] = 1.f;
  float a_cur = 1.f;
  float nLf = 0.f;
  int Lnext = 0, cacc = 0;

  const float K = 1.44269504088896340736f;
  const float LN2 = 0.69314718055994530942f;

  const float* sn = scores + (size_t)n * CD + (size_t)u * 5;
  const size_t str4 = 4 * tstr;

  auto CP = [&](int t, const f4a& qa, float qb) {
    const int rb = ((t + 1) & 1) * SD;
    const float vr = ap[rb + rdoff];    // pred read, conflict-free
    const float R = ap[rb];             // uniform addr -> broadcast
    const float p0 = dppq<0x00>(vr);    // A[p]
    const float p1 = dppq<0x55>(vr);    // A[256+p]
    const float p2 = dppq<0xAA>(vr);    // A[512+p]
    const float p3 = dppq<0xFF>(vr);    // A[768+p]
    float e0 = fexp2(__builtin_fmaf(qa.x, K, nLf));
    float e1 = fexp2(__builtin_fmaf(qa.y, K, nLf));
    float e2 = fexp2(__builtin_fmaf(qa.z, K, nLf));
    float e3 = fexp2(__builtin_fmaf(qa.w, K, nLf));
    float e4 = fexp2(__builtin_fmaf(qb,   K, nLf));
    float s = e0 * a_cur;
    s = __builtin_fmaf(e1, p0, s);
    s = __builtin_fmaf(e2, p1, s);
    s = __builtin_fmaf(e3, p2, s);
    s = __builtin_fmaf(e4, p3, s);
    a_cur = s;
    cacc += Lnext;
    ap[(t & 1) * SD + wroff] = s;
    const int xb = ((__float_as_int(R) >> 23) & 0xFF) - 127;
    Lnext = xb >> 2;                    // damped controller: lag 1, gain 1/4
    nLf = (float)(-Lnext);
    if (((t & 3) == 0) && (u == 0))     // publish progress for helpers
      __hip_atomic_store(&prog[n * 64], t, __ATOMIC_RELAXED,
                         __HIP_MEMORY_SCOPE_AGENT);
    asm volatile("s_waitcnt lgkmcnt(0)\n\ts_barrier" ::: "memory");
  };

#define PRO(cc)                                                             \
  const float* P##cc = sn + (size_t)((cc) < T ? (cc) : T - 1) * tstr;       \
  f4a qa##cc = *(const f4a*)P##cc;                                          \
  float qb##cc = P##cc[4];                                                  \
  P##cc += str4;
  PRO(0) PRO(1) PRO(2) PRO(3)
#undef PRO

  __syncthreads();

#define RL(cc)                                                              \
  qa##cc = *(const f4a*)P##cc;                                              \
  qb##cc = P##cc[4];                                                        \
  P##cc += str4;

  int t = 0;
  for (; t + 8 <= T; t += 4) {
    CP(t + 0, qa0, qb0); RL(0)
    CP(t + 1, qa1, qb1); RL(1)
    CP(t + 2, qa2, qb2); RL(2)
    CP(t + 3, qa3, qb3); RL(3)
  }
#undef RL

#define EPI1(cc)                                                            \
  if (t + (cc) < T) {                                                       \
    CP(t + (cc), qa##cc, qb##cc);                                           \
    if (t + 4 + (cc) < T) { qa##cc = *(const f4a*)P##cc; qb##cc = P##cc[4]; }\
  }
  EPI1(0) EPI1(1) EPI1(2) EPI1(3)
#undef EPI1
  t += 4;
#define EPI2(cc) if (t + (cc) < T) CP(t + (cc), qa##cc, qb##cc);
  EPI2(0) EPI2(1) EPI2(2) EPI2(3)
#undef EPI2

  if (u == 0)
    __hip_atomic_store(&prog[n * 64], DONE_S, __ATOMIC_RELAXED,
                       __HIP_MEMORY_SCOPE_AGENT);

  float v = a_cur;
#pragma unroll
  for (int d = 1; d < 64; d <<= 1) v += __shfl_xor(v, d, 64);
  if (lane == 0) red[wid] = v;
  __syncthreads();
  if (u == 0) {
    float ssum = red[0];
#pragma unroll
    for (int i = 1; i < 16; ++i) ssum += red[i];
    out[n] = LN2 * ((float)cacc + flog2(ssum));
  }
}

extern "C" void kernel_launch(void* const* d_in, const int* in_sizes, int n_in,
                              void* d_out, int out_size, void* d_ws, size_t ws_size,
                              hipStream_t stream) {
  const float* scores = (const float*)d_in[0];
  float* out = (float*)d_out;
  int* prog = (int*)d_ws;
  const long long tot = (long long)in_sizes[0];
  const int T = (int)(tot / ((long long)NB * CD));
  init_prog<<<dim3(1), dim3(64), 0, stream>>>(prog);
  ctc_logz<<<dim3(96), dim3(1024), 0, stream>>>(scores, out, prog, T);
}